// Round 14
// baseline (182.216 us; speedup 1.0000x reference)
//
#include <hip/hip_runtime.h>
#include <hip/hip_bf16.h>
#include <hip/hip_cooperative_groups.h>

namespace cg = cooperative_groups;

using bf16x8 = __attribute__((ext_vector_type(8))) __bf16;
using f32x4  = __attribute__((ext_vector_type(4))) float;

#define MTOT   16384
#define DMODEL 1024
#define DSTATE 64
#define KBIG   1088

__device__ __forceinline__ ushort f2b(float f) {
  __hip_bfloat16 h = __float2bfloat16(f);
  return *reinterpret_cast<ushort*>(&h);
}

// async global->LDS, 16 bytes per lane. LDS dest = wave-uniform base + lane*16.
__device__ __forceinline__ void gld_lds16(const ushort* g, const char* l) {
  using gptr_t = const __attribute__((address_space(1))) uint32_t*;
  using lptr_t = __attribute__((address_space(3))) uint32_t*;
  __builtin_amdgcn_global_load_lds(
      reinterpret_cast<gptr_t>(reinterpret_cast<uintptr_t>(g)),
      reinterpret_cast<lptr_t>(static_cast<uint32_t>(reinterpret_cast<uintptr_t>(l))),
      16, 0, 0);
}

#define BARRIER() do { asm volatile("" ::: "memory"); __builtin_amdgcn_s_barrier(); asm volatile("" ::: "memory"); } while (0)
#define VMCNT4() asm volatile("s_waitcnt vmcnt(4)" ::: "memory")
#define VMCNT0() asm volatile("s_waitcnt vmcnt(0)" ::: "memory")

// ================= mega (cooperative, 256 blocks x 256 thr, 1 blk/CU) =================
// P0: transpose-prep Wt/Btu/aSig (grid-stride over 288 tiles)  -> grid.sync
// P1: x -> Z bf16 cast; u = x@B (MFMA); raw u kept in LDS Ul; chunk carry -> global
//     -> threadfence + grid.sync
// P2: per-wave carry-prefix H (batched 16-wide loads); seeded scan h=a*h+u from Ul;
//     write bf16 h into Z[:,0:64]. No Uloc global round-trip.
__global__ __launch_bounds__(256) void mega(const float* __restrict__ x,
    const float* __restrict__ A_diag, const float* __restrict__ B,
    const float* __restrict__ C, const float* __restrict__ D,
    ushort* __restrict__ Wt, ushort* __restrict__ Btu, float* __restrict__ aSig,
    ushort* __restrict__ Z, float* __restrict__ carry) {
  __shared__ __align__(16) char smem_u[34816];
  float  (*tile)[65] = reinterpret_cast<float(*)[65]>(smem_u);      // P0 (16,640 B)
  ushort (*As)[136]  = reinterpret_cast<ushort(*)[136]>(smem_u);    // P1 (17,408 B)
  float  (*Ul)[68]   = reinterpret_cast<float(*)[68]>(smem_u + 17408); // P1/P2 (17,408 B)

  const int tid = threadIdx.x;
  const int w = tid >> 6, lane = tid & 63;
  const int l16 = lane & 15, lh = lane >> 4;

  // ---------------- P0: transpose prep ----------------
  if (blockIdx.x == 0 && tid < DSTATE) aSig[tid] = 1.0f / (1.0f + expf(-A_diag[tid]));
  {
    int r = tid >> 2;
    for (int job = blockIdx.x; job < 288; job += 256) {
      if (job < 272) {
        int bk = job % 17, bn = job / 17;
        int k0 = bk * 64, n0 = bn * 64;
        const float* srow = (k0 + r < DSTATE)
            ? (C + (size_t)(k0 + r) * DMODEL + n0)
            : (D + (size_t)(k0 + r - DSTATE) * DMODEL + n0);
#pragma unroll
        for (int it = 0; it < 4; ++it) {
          int c4 = (tid & 3) + it * 4;
          float4 v = *reinterpret_cast<const float4*>(srow + c4 * 4);
          tile[r][c4 * 4 + 0] = v.x; tile[r][c4 * 4 + 1] = v.y;
          tile[r][c4 * 4 + 2] = v.z; tile[r][c4 * 4 + 3] = v.w;
        }
        __syncthreads();
#pragma unroll
        for (int it = 0; it < 2; ++it) {
          int gq = (tid & 3) + it * 4;
          ushort o[8];
#pragma unroll
          for (int j = 0; j < 8; ++j) o[j] = f2b(tile[gq * 8 + j][r]);
          *reinterpret_cast<uint4*>(&Wt[(size_t)(n0 + r) * KBIG + k0 + gq * 8]) =
              *reinterpret_cast<uint4*>(o);
        }
      } else {
        int k0 = (job - 272) * 64;
        const float* srow = B + (size_t)(k0 + r) * DSTATE;
#pragma unroll
        for (int it = 0; it < 4; ++it) {
          int c4 = (tid & 3) + it * 4;
          float4 v = *reinterpret_cast<const float4*>(srow + c4 * 4);
          tile[r][c4 * 4 + 0] = v.x; tile[r][c4 * 4 + 1] = v.y;
          tile[r][c4 * 4 + 2] = v.z; tile[r][c4 * 4 + 3] = v.w;
        }
        __syncthreads();
#pragma unroll
        for (int it = 0; it < 2; ++it) {
          int gq = (tid & 3) + it * 4;
          ushort o[8];
#pragma unroll
          for (int j = 0; j < 8; ++j) o[j] = f2b(tile[gq * 8 + j][r]);
          *reinterpret_cast<uint4*>(&Btu[(size_t)r * DMODEL + k0 + gq * 8]) =
              *reinterpret_cast<uint4*>(o);
        }
      }
      __syncthreads();   // tile reuse guard (uniform trip count per block)
    }
  }

  cg::this_grid().sync();   // Wt/Btu/aSig visible grid-wide

  // ---------------- P1: x -> Z, u = x@B, carry ----------------
  const int row0 = blockIdx.x * 64;
  const int g = blockIdx.x * 4 + w;     // chunk id (16 rows)
  {
    f32x4 acc[4] = {};
    float4 xv[4][2];
#pragma unroll
    for (int p = 0; p < 4; ++p) {
      int fi = p * 256 + tid;
      int r = fi >> 4, kq = fi & 15;
      const float* src = x + (size_t)(row0 + r) * 1024 + kq * 8;
      xv[p][0] = *reinterpret_cast<const float4*>(src);
      xv[p][1] = *reinterpret_cast<const float4*>(src + 4);
    }
    for (int c = 0; c < 8; ++c) {
      int k0 = c * 128;
#pragma unroll
      for (int p = 0; p < 4; ++p) {
        int fi = p * 256 + tid;
        int r = fi >> 4, kq = fi & 15;
        ushort o[8] = {f2b(xv[p][0].x), f2b(xv[p][0].y), f2b(xv[p][0].z), f2b(xv[p][0].w),
                       f2b(xv[p][1].x), f2b(xv[p][1].y), f2b(xv[p][1].z), f2b(xv[p][1].w)};
        uint4 pk = *reinterpret_cast<uint4*>(o);
        *reinterpret_cast<uint4*>(&Z[(size_t)(row0 + r) * KBIG + DSTATE + k0 + kq * 8]) = pk;
        *reinterpret_cast<uint4*>(&As[r][kq * 8]) = pk;
      }
      __syncthreads();
      if (c < 7) {
        int k1 = k0 + 128;
#pragma unroll
        for (int p = 0; p < 4; ++p) {
          int fi = p * 256 + tid;
          int r = fi >> 4, kq = fi & 15;
          const float* src = x + (size_t)(row0 + r) * 1024 + k1 + kq * 8;
          xv[p][0] = *reinterpret_cast<const float4*>(src);
          xv[p][1] = *reinterpret_cast<const float4*>(src + 4);
        }
      }
#pragma unroll
      for (int ks = 0; ks < 4; ++ks) {
        bf16x8 af = *reinterpret_cast<const bf16x8*>(&As[w * 16 + l16][ks * 32 + lh * 8]);
#pragma unroll
        for (int n = 0; n < 4; ++n) {
          bf16x8 bf = *reinterpret_cast<const bf16x8*>(
              &Btu[(size_t)(n * 16 + l16) * 1024 + k0 + ks * 32 + lh * 8]);
          acc[n] = __builtin_amdgcn_mfma_f32_16x16x32_bf16(af, bf, acc[n], 0, 0, 0);
        }
      }
      __syncthreads();
    }
#pragma unroll
    for (int n = 0; n < 4; ++n)
#pragma unroll
      for (int j = 0; j < 4; ++j)
        Ul[w * 16 + lh * 4 + j][n * 16 + l16] = acc[n][j];
    // per-wave chunk carry (h0 = 0) — Ul rows w*16.. are wave-private
    float as = aSig[lane];
    float h = 0.0f;
#pragma unroll
    for (int i = 0; i < 16; ++i) h = fmaf(as, h, Ul[w * 16 + i][lane]);
    carry[(size_t)g * 64 + lane] = h;
  }

  __threadfence();
  cg::this_grid().sync();   // all carries visible

  // ---------------- P2: carry prefix + seeded scan -> Z[:,0:64] ----------------
  {
    int b = g >> 8, c = g & 255;
    float as = aSig[lane];
    float aL = as;
#pragma unroll
    for (int q = 0; q < 4; ++q) aL *= aL;  // as^16
    const float* cb = carry + ((size_t)b << 8) * 64 + lane;
    float H = 0.0f;
    for (int c0 = 0; c0 < 256; c0 += 16) {
      if (c0 >= c) break;                  // wave-uniform
      float v[16];
#pragma unroll
      for (int i = 0; i < 16; ++i) v[i] = cb[(size_t)(c0 + i) * 64];
#pragma unroll
      for (int i = 0; i < 16; ++i)
        if (c0 + i < c) H = fmaf(aL, H, v[i]);   // wave-uniform predicate
    }
    // seeded scan: h_{-1} = H, h_t = as*h + u_t (exact; Ul survived the grid sync)
    float h = H;
    size_t zbase = (size_t)(g * 16) * KBIG + lane;
#pragma unroll
    for (int i = 0; i < 16; ++i) {
      h = fmaf(as, h, Ul[w * 16 + i][lane]);
      Z[zbase + (size_t)i * KBIG] = f2b(h);
    }
  }
}

// ---------------- 256x256 8-phase GEMM: y = Z @ Wt^T (R5/R8-proven, LOCKED) ------
__global__ __launch_bounds__(512) void gemm256(const ushort* __restrict__ A, int lda,
                                               const ushort* __restrict__ Bt, int ldb,
                                               float* __restrict__ Cc, int ldc, int K) {
  extern __shared__ __align__(128) char smem[];
  const int tid = threadIdx.x;
  const int wid = tid >> 6, lane = tid & 63;
  const int wm = wid >> 2, wn = wid & 3;
  const int l16 = lane & 15, lh = lane >> 4;

  int bid = blockIdx.x;
  int swz = (bid & 7) * ((int)gridDim.x >> 3) + (bid >> 3);
  const int bmRow = (swz >> 2) * 256;
  const int bnCol = (swz & 3) * 256;

  const int NT = K / 64;

  const int cswz = ((lh ^ (l16 & 7)) << 4);
  const int sRow = lane >> 3;
  const int sCol = (((lane & 7) ^ (lane >> 3)) << 3);

  f32x4 acc[8][4] = {};
  bf16x8 aR[8], bR[8];

  auto stageA = [&](int buf, int t, int h) {
    size_t r = (size_t)(bmRow + h * 128 + wid * 8 + sRow);
    const ushort* g0 = A + r * (size_t)lda + t * 64 + sCol;
    const char* d = smem + buf * 65536 + (h * 128 + wid * 8) * 128;
    gld_lds16(g0, d);
    gld_lds16(g0 + (size_t)64 * lda, d + 64 * 128);
  };
  auto stageB = [&](int buf, int t, int h) {
    size_t r = (size_t)(bnCol + h * 128 + wid * 8 + sRow);
    const ushort* g0 = Bt + r * (size_t)ldb + t * 64 + sCol;
    const char* d = smem + buf * 65536 + 32768 + (h * 128 + wid * 8) * 128;
    gld_lds16(g0, d);
    gld_lds16(g0 + (size_t)64 * ldb, d + 64 * 128);
  };
  auto loadA = [&](int buf, int qm) {
#pragma unroll
    for (int m = 0; m < 4; ++m)
#pragma unroll
      for (int ks = 0; ks < 2; ++ks)
        aR[m * 2 + ks] = *reinterpret_cast<const bf16x8*>(
            smem + buf * 65536 + (wm * 128 + qm * 64 + m * 16 + l16) * 128 + (cswz ^ (ks * 64)));
  };
  auto loadB = [&](int buf, int qn) {
#pragma unroll
    for (int n = 0; n < 2; ++n)
#pragma unroll
      for (int ks = 0; ks < 2; ++ks)
        bR[qn * 4 + n * 2 + ks] = *reinterpret_cast<const bf16x8*>(
            smem + buf * 65536 + 32768 + (wn * 64 + qn * 32 + n * 16 + l16) * 128 + (cswz ^ (ks * 64)));
  };
  auto mfmaQ = [&](int qm, int qn) {
    __builtin_amdgcn_s_setprio(1);
    __builtin_amdgcn_sched_barrier(0);
#pragma unroll
    for (int ks = 0; ks < 2; ++ks)
#pragma unroll
      for (int m = 0; m < 4; ++m)
#pragma unroll
        for (int n = 0; n < 2; ++n)
          acc[qm * 4 + m][qn * 2 + n] = __builtin_amdgcn_mfma_f32_16x16x32_bf16(
              aR[m * 2 + ks], bR[qn * 4 + n * 2 + ks], acc[qm * 4 + m][qn * 2 + n], 0, 0, 0);
    __builtin_amdgcn_sched_barrier(0);
    __builtin_amdgcn_s_setprio(0);
  };

  stageA(0, 0, 0); stageA(0, 0, 1); stageB(0, 0, 0); stageB(0, 0, 1);
  if (1 < NT) { stageA(1, 1, 0); stageA(1, 1, 1); stageB(1, 1, 0); stageB(1, 1, 1); }
  VMCNT0();
  BARRIER();

  for (int t = 0; t < NT; t += 2) {
    const bool s01 = (t > 0) && (t + 1 < NT);
    const bool s23 = (t + 2 < NT);
    const bool s67 = (t + 3 < NT);
    loadA(0, 0); loadB(0, 0);
    if (s01) stageA(1, t + 1, 0);
    BARRIER(); mfmaQ(0, 0); BARRIER();
    loadB(0, 1);
    if (s01) stageA(1, t + 1, 1);
    BARRIER(); mfmaQ(0, 1); BARRIER();
    loadA(0, 1);
    if (s23) stageB(0, t + 2, 0);
    BARRIER(); mfmaQ(1, 0); BARRIER();
    if (s23) stageB(0, t + 2, 1);
    BARRIER(); mfmaQ(1, 1);
    if (s23) { VMCNT4(); } else { VMCNT0(); }
    BARRIER();
    if (t + 1 < NT) {
      loadA(1, 0); loadB(1, 0);
      if (s23) stageA(0, t + 2, 0);
      BARRIER(); mfmaQ(0, 0); BARRIER();
      loadB(1, 1);
      if (s23) stageA(0, t + 2, 1);
      BARRIER(); mfmaQ(0, 1); BARRIER();
      loadA(1, 1);
      if (s67) stageB(1, t + 3, 0);
      BARRIER(); mfmaQ(1, 0); BARRIER();
      if (s67) stageB(1, t + 3, 1);
      BARRIER(); mfmaQ(1, 1);
      if (s67) { VMCNT4(); } else { VMCNT0(); }
      BARRIER();
    }
  }

#pragma unroll
  for (int i = 0; i < 8; ++i)
#pragma unroll
    for (int jn = 0; jn < 4; ++jn)
#pragma unroll
      for (int j = 0; j < 4; ++j) {
        int r = bmRow + wm * 128 + (i >> 2) * 64 + (i & 3) * 16 + lh * 4 + j;
        int c = bnCol + wn * 64 + (jn >> 1) * 32 + (jn & 1) * 16 + l16;
        Cc[(size_t)r * ldc + c] = acc[i][jn][j];
      }
}

extern "C" void kernel_launch(void* const* d_in, const int* in_sizes, int n_in,
                              void* d_out, int out_size, void* d_ws, size_t ws_size,
                              hipStream_t stream) {
  const float* x      = (const float*)d_in[0];
  const float* A_diag = (const float*)d_in[1];
  const float* B      = (const float*)d_in[2];
  const float* C      = (const float*)d_in[3];
  const float* D      = (const float*)d_in[4];
  float* y = (float*)d_out;

  char* w = (char*)d_ws;
  ushort* Z     = (ushort*)(w);                 // [16384][1088] bf16  35,651,584
  ushort* Wt    = (ushort*)(w + 35651584);      // [1024][1088] bf16    2,228,224
  ushort* Btu   = (ushort*)(w + 37879808);      // [64][1024] bf16        131,072
  float*  carry = (float*) (w + 38010880);      // [1024][64] f32         262,144
  float*  aSig  = (float*) (w + 38273024);      // [64] f32

  (void)hipFuncSetAttribute(reinterpret_cast<const void*>(&gemm256),
                            hipFuncAttributeMaxDynamicSharedMemorySize, 131072);

  void* args[] = {(void*)&x, (void*)&A_diag, (void*)&B, (void*)&C, (void*)&D,
                  (void*)&Wt, (void*)&Btu, (void*)&aSig, (void*)&Z, (void*)&carry};
  (void)hipLaunchCooperativeKernel(reinterpret_cast<void*>(&mega),
                                   dim3(256), dim3(256), args, 0, stream);
  // y = [h|x] @ [C;D] : M=16384, N=1024, K=1088  (256x256 tiles -> 256 blocks)
  gemm256<<<dim3(64 * 4), dim3(512), 131072, stream>>>(Z, KBIG, Wt, KBIG, y, DMODEL, KBIG);
}

// Round 15
// 86.316 us; speedup vs baseline: 2.1110x; 2.1110x over previous
//
#include <hip/hip_runtime.h>
#include <hip/hip_bf16.h>

using bf16x8 = __attribute__((ext_vector_type(8))) __bf16;
using f32x4  = __attribute__((ext_vector_type(4))) float;

#define MTOT   16384
#define DMODEL 1024
#define DSTATE 64
#define KBIG   1088

__device__ __forceinline__ ushort f2b(float f) {
  __hip_bfloat16 h = __float2bfloat16(f);
  return *reinterpret_cast<ushort*>(&h);
}

// async global->LDS, 16 bytes per lane. LDS dest = wave-uniform base + lane*16.
__device__ __forceinline__ void gld_lds16(const ushort* g, const char* l) {
  using gptr_t = const __attribute__((address_space(1))) uint32_t*;
  using lptr_t = __attribute__((address_space(3))) uint32_t*;
  __builtin_amdgcn_global_load_lds(
      reinterpret_cast<gptr_t>(reinterpret_cast<uintptr_t>(g)),
      reinterpret_cast<lptr_t>(static_cast<uint32_t>(reinterpret_cast<uintptr_t>(l))),
      16, 0, 0);
}

#define BARRIER() do { asm volatile("" ::: "memory"); __builtin_amdgcn_s_barrier(); asm volatile("" ::: "memory"); } while (0)
#define VMCNT4() asm volatile("s_waitcnt vmcnt(4)" ::: "memory")
#define VMCNT0() asm volatile("s_waitcnt vmcnt(0)" ::: "memory")

// ---------------- prep: coalesced tile-transpose for Wt, Btu; aSig (R12-proven) --------
__global__ __launch_bounds__(256) void prep_wb(const float* __restrict__ A_diag,
    const float* __restrict__ B, const float* __restrict__ C, const float* __restrict__ D,
    ushort* __restrict__ Wt, ushort* __restrict__ Btu, float* __restrict__ aSig) {
  __shared__ float tile[64][65];
  int bid = blockIdx.x;
  int tid = threadIdx.x;
  int r = tid >> 2;
  if (bid < 272) {
    int bk = bid % 17, bn = bid / 17;
    int k0 = bk * 64, n0 = bn * 64;
    const float* srow = (k0 + r < DSTATE)
        ? (C + (size_t)(k0 + r) * DMODEL + n0)
        : (D + (size_t)(k0 + r - DSTATE) * DMODEL + n0);
#pragma unroll
    for (int it = 0; it < 4; ++it) {
      int c4 = (tid & 3) + it * 4;
      float4 v = *reinterpret_cast<const float4*>(srow + c4 * 4);
      tile[r][c4 * 4 + 0] = v.x; tile[r][c4 * 4 + 1] = v.y;
      tile[r][c4 * 4 + 2] = v.z; tile[r][c4 * 4 + 3] = v.w;
    }
    __syncthreads();
#pragma unroll
    for (int it = 0; it < 2; ++it) {
      int gq = (tid & 3) + it * 4;  // 8-k group 0..7
      ushort o[8];
#pragma unroll
      for (int j = 0; j < 8; ++j) o[j] = f2b(tile[gq * 8 + j][r]);
      *reinterpret_cast<uint4*>(&Wt[(size_t)(n0 + r) * KBIG + k0 + gq * 8]) =
          *reinterpret_cast<uint4*>(o);
    }
  } else {
    int k0 = (bid - 272) * 64;
    const float* srow = B + (size_t)(k0 + r) * DSTATE;
#pragma unroll
    for (int it = 0; it < 4; ++it) {
      int c4 = (tid & 3) + it * 4;
      float4 v = *reinterpret_cast<const float4*>(srow + c4 * 4);
      tile[r][c4 * 4 + 0] = v.x; tile[r][c4 * 4 + 1] = v.y;
      tile[r][c4 * 4 + 2] = v.z; tile[r][c4 * 4 + 3] = v.w;
    }
    __syncthreads();
#pragma unroll
    for (int it = 0; it < 2; ++it) {
      int gq = (tid & 3) + it * 4;
      ushort o[8];
#pragma unroll
      for (int j = 0; j < 8; ++j) o[j] = f2b(tile[gq * 8 + j][r]);
      *reinterpret_cast<uint4*>(&Btu[(size_t)r * DMODEL + k0 + gq * 8]) =
          *reinterpret_cast<uint4*>(o);
    }
    if (bid == 272 && tid < DSTATE) aSig[tid] = 1.0f / (1.0f + expf(-A_diag[tid]));
  }
}

// ---------------- fused (R8/R13-proven cooperative): x -> Z(bf16), u = x@B, scan -------
__global__ __launch_bounds__(256) void fused_xu(const float* __restrict__ x,
    const ushort* __restrict__ Btu, const float* __restrict__ aSig,
    ushort* __restrict__ Z, float* __restrict__ Uloc, float* __restrict__ carry) {
  __shared__ ushort As[64][136];
  __shared__ float  Ul[64][68];
  int tid = threadIdx.x;
  int w = tid >> 6, lane = tid & 63;
  int l16 = lane & 15, lh = lane >> 4;
  int row0 = blockIdx.x * 64;

  f32x4 acc[4] = {};
  float4 xv[4][2];
#pragma unroll
  for (int p = 0; p < 4; ++p) {
    int fi = p * 256 + tid;
    int r = fi >> 4, kq = fi & 15;
    const float* src = x + (size_t)(row0 + r) * 1024 + kq * 8;
    xv[p][0] = *reinterpret_cast<const float4*>(src);
    xv[p][1] = *reinterpret_cast<const float4*>(src + 4);
  }
  for (int c = 0; c < 8; ++c) {
    int k0 = c * 128;
#pragma unroll
    for (int p = 0; p < 4; ++p) {
      int fi = p * 256 + tid;
      int r = fi >> 4, kq = fi & 15;
      ushort o[8] = {f2b(xv[p][0].x), f2b(xv[p][0].y), f2b(xv[p][0].z), f2b(xv[p][0].w),
                     f2b(xv[p][1].x), f2b(xv[p][1].y), f2b(xv[p][1].z), f2b(xv[p][1].w)};
      uint4 pk = *reinterpret_cast<uint4*>(o);
      *reinterpret_cast<uint4*>(&Z[(size_t)(row0 + r) * KBIG + DSTATE + k0 + kq * 8]) = pk;
      *reinterpret_cast<uint4*>(&As[r][kq * 8]) = pk;
    }
    __syncthreads();
    if (c < 7) {
      int k1 = k0 + 128;
#pragma unroll
      for (int p = 0; p < 4; ++p) {
        int fi = p * 256 + tid;
        int r = fi >> 4, kq = fi & 15;
        const float* src = x + (size_t)(row0 + r) * 1024 + k1 + kq * 8;
        xv[p][0] = *reinterpret_cast<const float4*>(src);
        xv[p][1] = *reinterpret_cast<const float4*>(src + 4);
      }
    }
#pragma unroll
    for (int ks = 0; ks < 4; ++ks) {
      bf16x8 af = *reinterpret_cast<const bf16x8*>(&As[w * 16 + l16][ks * 32 + lh * 8]);
#pragma unroll
      for (int n = 0; n < 4; ++n) {
        bf16x8 bf = *reinterpret_cast<const bf16x8*>(
            &Btu[(size_t)(n * 16 + l16) * 1024 + k0 + ks * 32 + lh * 8]);
        acc[n] = __builtin_amdgcn_mfma_f32_16x16x32_bf16(af, bf, acc[n], 0, 0, 0);
      }
    }
    __syncthreads();
  }
#pragma unroll
  for (int n = 0; n < 4; ++n)
#pragma unroll
    for (int j = 0; j < 4; ++j)
      Ul[w * 16 + lh * 4 + j][n * 16 + l16] = acc[n][j];
  __syncthreads();
  int s = lane;
  float as = aSig[s];
  float h = 0.0f;
  int g = blockIdx.x * 4 + w;
#pragma unroll
  for (int i = 0; i < 16; ++i) {
    h = fmaf(as, h, Ul[w * 16 + i][s]);
    Uloc[(size_t)(g * 16 + i) * 64 + s] = h;
  }
  carry[(size_t)g * 64 + s] = h;
}

// ---------------- scan fix (merged): redundant batched prefix + apply + write Z ------
__global__ __launch_bounds__(256) void scan_fix2(const float* __restrict__ aSig,
    const float* __restrict__ Uloc, const float* __restrict__ carry,
    ushort* __restrict__ Z) {
  int w = threadIdx.x >> 6, s = threadIdx.x & 63;
  int g = blockIdx.x * 4 + w;          // 0..1023
  int b = g >> 8, c = g & 255;
  float as = aSig[s];
  float aL = as;
#pragma unroll
  for (int q = 0; q < 4; ++q) aL *= aL;  // as^16
  const float* cb = carry + ((size_t)b << 8) * 64 + s;
  float H = 0.0f;
  for (int c0 = 0; c0 < 256; c0 += 16) {
    if (c0 >= c) break;                  // wave-uniform
    float v[16];
#pragma unroll
    for (int i = 0; i < 16; ++i) v[i] = cb[(size_t)(c0 + i) * 64];
#pragma unroll
    for (int i = 0; i < 16; ++i)
      if (c0 + i < c) H = fmaf(aL, H, v[i]);   // wave-uniform predicate
  }
  float p = as;
  size_t ubase = (size_t)g * 16 * 64 + s;
  size_t zbase = (size_t)(g * 16) * KBIG + s;
#pragma unroll
  for (int i = 0; i < 16; ++i) {
    float h = fmaf(p, H, Uloc[ubase + (size_t)i * 64]);
    p *= as;
    Z[zbase + (size_t)i * KBIG] = f2b(h);
  }
}

// ---------------- 128x128 GEMM, full-dbuf LDS, 2 blocks/CU: y = Z @ Wt^T ----------------
// Clean test of cross-block TLP (m114): 1024 blocks, 64KB LDS, <=128 VGPR via
// __launch_bounds__(512,4) -> 2 co-resident blocks/CU whose LDS/barrier drains
// overlap each other's MFMA. Both operands LDS-staged with the R5-proven
// swizzle (conflict-free); stage t+2 two-ahead; vmcnt(4) counted.
// 8 waves (2x4), wave tile 64x32: acc[4][2]=32 + frags 48 VGPR -> no spill.
__global__ __launch_bounds__(512, 4) void gemm128(const ushort* __restrict__ A, int lda,
                                                  const ushort* __restrict__ Bt, int ldb,
                                                  float* __restrict__ Cc, int ldc, int K) {
  extern __shared__ __align__(128) char smem[];  // buf{0,1} x (A 16K + B 16K) = 64 KB
  const int tid = threadIdx.x;
  const int wid = tid >> 6, lane = tid & 63;
  const int wm = wid >> 2, wn = wid & 3;
  const int l16 = lane & 15, lh = lane >> 4;

  int bid = blockIdx.x;
  int swz = (bid & 7) * ((int)gridDim.x >> 3) + (bid >> 3);  // 1024 % 8 == 0
  const int bmRow = (swz >> 3) * 128;   // 128 row-tiles
  const int bnCol = (swz & 7) * 128;    // 8 col-tiles
  const int NT = K / 64;                // 17

  const int cswz = ((lh ^ (l16 & 7)) << 4);
  const int sRow = lane >> 3;
  const int sCol = (((lane & 7) ^ (lane >> 3)) << 3);

  const ushort* aBase = A + (size_t)(bmRow + wid * 8 + sRow) * lda + sCol;
  const ushort* bBase = Bt + (size_t)(bnCol + wid * 8 + sRow) * ldb + sCol;

  f32x4 acc[4][2] = {};
  bf16x8 aR[8], bR[4];

  auto stageA = [&](int buf, int t) {      // 128 rows = 2 block-wide calls
    const ushort* g = aBase + (size_t)t * 64;
    char* d = smem + buf * 32768 + (wid * 8) * 128;
    gld_lds16(g, d);
    gld_lds16(g + (size_t)64 * lda, d + 64 * 128);
  };
  auto stageB = [&](int buf, int t) {
    const ushort* g = bBase + (size_t)t * 64;
    char* d = smem + buf * 32768 + 16384 + (wid * 8) * 128;
    gld_lds16(g, d);
    gld_lds16(g + (size_t)64 * ldb, d + 64 * 128);
  };
  auto readA = [&](int buf) {
#pragma unroll
    for (int m = 0; m < 4; ++m)
#pragma unroll
      for (int ks = 0; ks < 2; ++ks)
        aR[m * 2 + ks] = *reinterpret_cast<const bf16x8*>(
            smem + buf * 32768 + (wm * 64 + m * 16 + l16) * 128 + (cswz ^ (ks * 64)));
  };
  auto readB = [&](int buf) {
#pragma unroll
    for (int n = 0; n < 2; ++n)
#pragma unroll
      for (int ks = 0; ks < 2; ++ks)
        bR[n * 2 + ks] = *reinterpret_cast<const bf16x8*>(
            smem + buf * 32768 + 16384 + (wn * 32 + n * 16 + l16) * 128 + (cswz ^ (ks * 64)));
  };

  // prologue: stage tiles 0,1; drain tile0 (tile1's 4 calls stay in flight)
  stageA(0, 0); stageB(0, 0);
  stageA(1, 1); stageB(1, 1);
  VMCNT4();
  BARRIER();

  for (int t = 0; t < NT; ++t) {
    const int buf = t & 1;
    const bool st2 = (t + 2 < NT);
    readA(buf); readB(buf);
    BARRIER();                     // all reads of buf issued block-wide
    if (st2) { stageA(buf, t + 2); stageB(buf, t + 2); }
    __builtin_amdgcn_s_setprio(1);
#pragma unroll
    for (int ks = 0; ks < 2; ++ks)
#pragma unroll
      for (int m = 0; m < 4; ++m)
#pragma unroll
        for (int n = 0; n < 2; ++n)
          acc[m][n] = __builtin_amdgcn_mfma_f32_16x16x32_bf16(
              aR[m * 2 + ks], bR[n * 2 + ks], acc[m][n], 0, 0, 0);
    __builtin_amdgcn_s_setprio(0);
    if (st2) { VMCNT4(); } else { VMCNT0(); }   // drain t+1's stages; t+2's in flight
    BARRIER();                     // publish buf^1 (tile t+1)
  }

  // epilogue: C/D 16x16 layout: col = l16, row = lh*4 + j
#pragma unroll
  for (int m = 0; m < 4; ++m)
#pragma unroll
    for (int n = 0; n < 2; ++n)
#pragma unroll
      for (int j = 0; j < 4; ++j) {
        int r = bmRow + wm * 64 + m * 16 + lh * 4 + j;
        int c = bnCol + wn * 32 + n * 16 + l16;
        Cc[(size_t)r * ldc + c] = acc[m][n][j];
      }
}

extern "C" void kernel_launch(void* const* d_in, const int* in_sizes, int n_in,
                              void* d_out, int out_size, void* d_ws, size_t ws_size,
                              hipStream_t stream) {
  const float* x      = (const float*)d_in[0];
  const float* A_diag = (const float*)d_in[1];
  const float* B      = (const float*)d_in[2];
  const float* C      = (const float*)d_in[3];
  const float* D      = (const float*)d_in[4];
  float* y = (float*)d_out;

  char* w = (char*)d_ws;
  ushort* Z     = (ushort*)(w);                 // [16384][1088] bf16  35,651,584
  ushort* Wt    = (ushort*)(w + 35651584);      // [1024][1088] bf16    2,228,224
  ushort* Btu   = (ushort*)(w + 37879808);      // [64][1024] bf16        131,072
  float*  Uloc  = (float*) (w + 38010880);      // [16384][64] f32      4,194,304
  float*  carry = (float*) (w + 42205184);      // [1024][64] f32         262,144
  float*  aSig  = (float*) (w + 42467328);      // [64] f32

  (void)hipFuncSetAttribute(reinterpret_cast<const void*>(&gemm128),
                            hipFuncAttributeMaxDynamicSharedMemorySize, 65536);

  prep_wb<<<dim3(288), dim3(256), 0, stream>>>(A_diag, B, C, D, Wt, Btu, aSig);
  fused_xu<<<dim3(256), dim3(256), 0, stream>>>(x, Btu, aSig, Z, Uloc, carry);
  scan_fix2<<<dim3(256), dim3(256), 0, stream>>>(aSig, Uloc, carry, Z);
  // y = [h|x] @ [C;D] : M=16384, N=1024, K=1088  (128x128 tiles -> 1024 blocks, 2/CU)
  gemm128<<<dim3(128 * 8), dim3(512), 65536, stream>>>(Z, KBIG, Wt, KBIG, y, DMODEL, KBIG);
}

// Round 16
// 84.342 us; speedup vs baseline: 2.1604x; 1.0234x over previous
//
#include <hip/hip_runtime.h>
#include <hip/hip_bf16.h>

using bf16x8 = __attribute__((ext_vector_type(8))) __bf16;
using f32x4  = __attribute__((ext_vector_type(4))) float;

#define MTOT   16384
#define DMODEL 1024
#define DSTATE 64
#define KBIG   1088

__device__ __forceinline__ ushort f2b(float f) {
  __hip_bfloat16 h = __float2bfloat16(f);
  return *reinterpret_cast<ushort*>(&h);
}

// async global->LDS, 16 bytes per lane. LDS dest = wave-uniform base + lane*16.
__device__ __forceinline__ void gld_lds16(const ushort* g, const char* l) {
  using gptr_t = const __attribute__((address_space(1))) uint32_t*;
  using lptr_t = __attribute__((address_space(3))) uint32_t*;
  __builtin_amdgcn_global_load_lds(
      reinterpret_cast<gptr_t>(reinterpret_cast<uintptr_t>(g)),
      reinterpret_cast<lptr_t>(static_cast<uint32_t>(reinterpret_cast<uintptr_t>(l))),
      16, 0, 0);
}

#define BARRIER() do { asm volatile("" ::: "memory"); __builtin_amdgcn_s_barrier(); asm volatile("" ::: "memory"); } while (0)
#define VMCNT4() asm volatile("s_waitcnt vmcnt(4)" ::: "memory")
#define VMCNT0() asm volatile("s_waitcnt vmcnt(0)" ::: "memory")

// ---------------- prep: coalesced tile-transpose for Wt, Btu; aSig (R12-proven) --------
__global__ __launch_bounds__(256) void prep_wb(const float* __restrict__ A_diag,
    const float* __restrict__ B, const float* __restrict__ C, const float* __restrict__ D,
    ushort* __restrict__ Wt, ushort* __restrict__ Btu, float* __restrict__ aSig) {
  __shared__ float tile[64][65];
  int bid = blockIdx.x;
  int tid = threadIdx.x;
  int r = tid >> 2;
  if (bid < 272) {
    int bk = bid % 17, bn = bid / 17;
    int k0 = bk * 64, n0 = bn * 64;
    const float* srow = (k0 + r < DSTATE)
        ? (C + (size_t)(k0 + r) * DMODEL + n0)
        : (D + (size_t)(k0 + r - DSTATE) * DMODEL + n0);
#pragma unroll
    for (int it = 0; it < 4; ++it) {
      int c4 = (tid & 3) + it * 4;
      float4 v = *reinterpret_cast<const float4*>(srow + c4 * 4);
      tile[r][c4 * 4 + 0] = v.x; tile[r][c4 * 4 + 1] = v.y;
      tile[r][c4 * 4 + 2] = v.z; tile[r][c4 * 4 + 3] = v.w;
    }
    __syncthreads();
#pragma unroll
    for (int it = 0; it < 2; ++it) {
      int gq = (tid & 3) + it * 4;  // 8-k group 0..7
      ushort o[8];
#pragma unroll
      for (int j = 0; j < 8; ++j) o[j] = f2b(tile[gq * 8 + j][r]);
      *reinterpret_cast<uint4*>(&Wt[(size_t)(n0 + r) * KBIG + k0 + gq * 8]) =
          *reinterpret_cast<uint4*>(o);
    }
  } else {
    int k0 = (bid - 272) * 64;
    const float* srow = B + (size_t)(k0 + r) * DSTATE;
#pragma unroll
    for (int it = 0; it < 4; ++it) {
      int c4 = (tid & 3) + it * 4;
      float4 v = *reinterpret_cast<const float4*>(srow + c4 * 4);
      tile[r][c4 * 4 + 0] = v.x; tile[r][c4 * 4 + 1] = v.y;
      tile[r][c4 * 4 + 2] = v.z; tile[r][c4 * 4 + 3] = v.w;
    }
    __syncthreads();
#pragma unroll
    for (int it = 0; it < 2; ++it) {
      int gq = (tid & 3) + it * 4;
      ushort o[8];
#pragma unroll
      for (int j = 0; j < 8; ++j) o[j] = f2b(tile[gq * 8 + j][r]);
      *reinterpret_cast<uint4*>(&Btu[(size_t)r * DMODEL + k0 + gq * 8]) =
          *reinterpret_cast<uint4*>(o);
    }
    if (bid == 272 && tid < DSTATE) aSig[tid] = 1.0f / (1.0f + expf(-A_diag[tid]));
  }
}

// ---------------- fused v2 (2 blocks/CU): x -> Z(bf16), u = x@B, chunk scan ----------
// 512 blocks x 32 rows, 4 waves. LDS 17.4KB -> 2 co-resident blocks/CU (TLP hides
// HBM latency; was grid-capped at 1/CU). Wave (w>>1) owns A-frag rows {0-15|16-31},
// wave (w&1) owns B states {0-31|32-63}: 2 acc/wave, same total MFMA.
// Chunk ids g = bid*2 + {0,1} preserve global 1024-chunk order for scan_fix2.
__global__ __launch_bounds__(256) void fused_xu(const float* __restrict__ x,
    const ushort* __restrict__ Btu, const float* __restrict__ aSig,
    ushort* __restrict__ Z, float* __restrict__ Uloc, float* __restrict__ carry) {
  __shared__ ushort As[32][136];
  __shared__ float  Ul[32][68];
  int tid = threadIdx.x;
  int w = tid >> 6, lane = tid & 63;
  int l16 = lane & 15, lh = lane >> 4;
  int row0 = blockIdx.x * 32;
  int cr0 = (w >> 1) * 16;   // A-frag row base
  int nb = (w & 1) * 2;      // B n-base (states nb*16..nb*16+31)

  f32x4 acc[2] = {};
  float4 xv[2][2];
#pragma unroll
  for (int p = 0; p < 2; ++p) {
    int fi = p * 256 + tid;
    int r = fi >> 4, kq = fi & 15;
    const float* src = x + (size_t)(row0 + r) * 1024 + kq * 8;
    xv[p][0] = *reinterpret_cast<const float4*>(src);
    xv[p][1] = *reinterpret_cast<const float4*>(src + 4);
  }
  for (int c = 0; c < 8; ++c) {
    int k0 = c * 128;
#pragma unroll
    for (int p = 0; p < 2; ++p) {
      int fi = p * 256 + tid;
      int r = fi >> 4, kq = fi & 15;
      ushort o[8] = {f2b(xv[p][0].x), f2b(xv[p][0].y), f2b(xv[p][0].z), f2b(xv[p][0].w),
                     f2b(xv[p][1].x), f2b(xv[p][1].y), f2b(xv[p][1].z), f2b(xv[p][1].w)};
      uint4 pk = *reinterpret_cast<uint4*>(o);
      *reinterpret_cast<uint4*>(&Z[(size_t)(row0 + r) * KBIG + DSTATE + k0 + kq * 8]) = pk;
      *reinterpret_cast<uint4*>(&As[r][kq * 8]) = pk;
    }
    __syncthreads();
    if (c < 7) {
      int k1 = k0 + 128;
#pragma unroll
      for (int p = 0; p < 2; ++p) {
        int fi = p * 256 + tid;
        int r = fi >> 4, kq = fi & 15;
        const float* src = x + (size_t)(row0 + r) * 1024 + k1 + kq * 8;
        xv[p][0] = *reinterpret_cast<const float4*>(src);
        xv[p][1] = *reinterpret_cast<const float4*>(src + 4);
      }
    }
#pragma unroll
    for (int ks = 0; ks < 4; ++ks) {
      bf16x8 af = *reinterpret_cast<const bf16x8*>(&As[cr0 + l16][ks * 32 + lh * 8]);
#pragma unroll
      for (int n2 = 0; n2 < 2; ++n2) {
        bf16x8 bf = *reinterpret_cast<const bf16x8*>(
            &Btu[(size_t)((nb + n2) * 16 + l16) * 1024 + k0 + ks * 32 + lh * 8]);
        acc[n2] = __builtin_amdgcn_mfma_f32_16x16x32_bf16(af, bf, acc[n2], 0, 0, 0);
      }
    }
    __syncthreads();
  }
#pragma unroll
  for (int n2 = 0; n2 < 2; ++n2)
#pragma unroll
    for (int j = 0; j < 4; ++j)
      Ul[cr0 + lh * 4 + j][(nb + n2) * 16 + l16] = acc[n2][j];
  __syncthreads();
  if (w < 2) {   // wave w scans chunk bid*2+w (rows w*16..w*16+15)
    int g = blockIdx.x * 2 + w;
    float as = aSig[lane];
    float h = 0.0f;
#pragma unroll
    for (int i = 0; i < 16; ++i) {
      h = fmaf(as, h, Ul[w * 16 + i][lane]);
      Uloc[(size_t)(g * 16 + i) * 64 + lane] = h;
    }
    carry[(size_t)g * 64 + lane] = h;
  }
}

// ---------------- scan fix (merged): redundant batched prefix + apply + write Z ------
__global__ __launch_bounds__(256) void scan_fix2(const float* __restrict__ aSig,
    const float* __restrict__ Uloc, const float* __restrict__ carry,
    ushort* __restrict__ Z) {
  int w = threadIdx.x >> 6, s = threadIdx.x & 63;
  int g = blockIdx.x * 4 + w;          // 0..1023
  int b = g >> 8, c = g & 255;
  float as = aSig[s];
  float aL = as;
#pragma unroll
  for (int q = 0; q < 4; ++q) aL *= aL;  // as^16
  const float* cb = carry + ((size_t)b << 8) * 64 + s;
  float H = 0.0f;
  for (int c0 = 0; c0 < 256; c0 += 16) {
    if (c0 >= c) break;                  // wave-uniform
    float v[16];
#pragma unroll
    for (int i = 0; i < 16; ++i) v[i] = cb[(size_t)(c0 + i) * 64];
#pragma unroll
    for (int i = 0; i < 16; ++i)
      if (c0 + i < c) H = fmaf(aL, H, v[i]);   // wave-uniform predicate
  }
  float p = as;
  size_t ubase = (size_t)g * 16 * 64 + s;
  size_t zbase = (size_t)(g * 16) * KBIG + s;
#pragma unroll
  for (int i = 0; i < 16; ++i) {
    float h = fmaf(p, H, Uloc[ubase + (size_t)i * 64]);
    p *= as;
    Z[zbase + (size_t)i * KBIG] = f2b(h);
  }
}

// ---------------- 128x128 GEMM, full-dbuf LDS, 2 blocks/CU (R15-proven, LOCKED) --------
__global__ __launch_bounds__(512, 4) void gemm128(const ushort* __restrict__ A, int lda,
                                                  const ushort* __restrict__ Bt, int ldb,
                                                  float* __restrict__ Cc, int ldc, int K) {
  extern __shared__ __align__(128) char smem[];  // buf{0,1} x (A 16K + B 16K) = 64 KB
  const int tid = threadIdx.x;
  const int wid = tid >> 6, lane = tid & 63;
  const int wm = wid >> 2, wn = wid & 3;
  const int l16 = lane & 15, lh = lane >> 4;

  int bid = blockIdx.x;
  int swz = (bid & 7) * ((int)gridDim.x >> 3) + (bid >> 3);  // 1024 % 8 == 0
  const int bmRow = (swz >> 3) * 128;
  const int bnCol = (swz & 7) * 128;
  const int NT = K / 64;                // 17

  const int cswz = ((lh ^ (l16 & 7)) << 4);
  const int sRow = lane >> 3;
  const int sCol = (((lane & 7) ^ (lane >> 3)) << 3);

  const ushort* aBase = A + (size_t)(bmRow + wid * 8 + sRow) * lda + sCol;
  const ushort* bBase = Bt + (size_t)(bnCol + wid * 8 + sRow) * ldb + sCol;

  f32x4 acc[4][2] = {};
  bf16x8 aR[8], bR[4];

  auto stageA = [&](int buf, int t) {
    const ushort* g = aBase + (size_t)t * 64;
    char* d = smem + buf * 32768 + (wid * 8) * 128;
    gld_lds16(g, d);
    gld_lds16(g + (size_t)64 * lda, d + 64 * 128);
  };
  auto stageB = [&](int buf, int t) {
    const ushort* g = bBase + (size_t)t * 64;
    char* d = smem + buf * 32768 + 16384 + (wid * 8) * 128;
    gld_lds16(g, d);
    gld_lds16(g + (size_t)64 * ldb, d + 64 * 128);
  };
  auto readA = [&](int buf) {
#pragma unroll
    for (int m = 0; m < 4; ++m)
#pragma unroll
      for (int ks = 0; ks < 2; ++ks)
        aR[m * 2 + ks] = *reinterpret_cast<const bf16x8*>(
            smem + buf * 32768 + (wm * 64 + m * 16 + l16) * 128 + (cswz ^ (ks * 64)));
  };
  auto readB = [&](int buf) {
#pragma unroll
    for (int n = 0; n < 2; ++n)
#pragma unroll
      for (int ks = 0; ks < 2; ++ks)
        bR[n * 2 + ks] = *reinterpret_cast<const bf16x8*>(
            smem + buf * 32768 + 16384 + (wn * 32 + n * 16 + l16) * 128 + (cswz ^ (ks * 64)));
  };

  stageA(0, 0); stageB(0, 0);
  stageA(1, 1); stageB(1, 1);
  VMCNT4();
  BARRIER();

  for (int t = 0; t < NT; ++t) {
    const int buf = t & 1;
    const bool st2 = (t + 2 < NT);
    readA(buf); readB(buf);
    BARRIER();
    if (st2) { stageA(buf, t + 2); stageB(buf, t + 2); }
    __builtin_amdgcn_s_setprio(1);
#pragma unroll
    for (int ks = 0; ks < 2; ++ks)
#pragma unroll
      for (int m = 0; m < 4; ++m)
#pragma unroll
        for (int n = 0; n < 2; ++n)
          acc[m][n] = __builtin_amdgcn_mfma_f32_16x16x32_bf16(
              aR[m * 2 + ks], bR[n * 2 + ks], acc[m][n], 0, 0, 0);
    __builtin_amdgcn_s_setprio(0);
    if (st2) { VMCNT4(); } else { VMCNT0(); }
    BARRIER();
  }

#pragma unroll
  for (int m = 0; m < 4; ++m)
#pragma unroll
    for (int n = 0; n < 2; ++n)
#pragma unroll
      for (int j = 0; j < 4; ++j) {
        int r = bmRow + wm * 64 + m * 16 + lh * 4 + j;
        int c = bnCol + wn * 32 + n * 16 + l16;
        Cc[(size_t)r * ldc + c] = acc[m][n][j];
      }
}

extern "C" void kernel_launch(void* const* d_in, const int* in_sizes, int n_in,
                              void* d_out, int out_size, void* d_ws, size_t ws_size,
                              hipStream_t stream) {
  const float* x      = (const float*)d_in[0];
  const float* A_diag = (const float*)d_in[1];
  const float* B      = (const float*)d_in[2];
  const float* C      = (const float*)d_in[3];
  const float* D      = (const float*)d_in[4];
  float* y = (float*)d_out;

  char* w = (char*)d_ws;
  ushort* Z     = (ushort*)(w);                 // [16384][1088] bf16  35,651,584
  ushort* Wt    = (ushort*)(w + 35651584);      // [1024][1088] bf16    2,228,224
  ushort* Btu   = (ushort*)(w + 37879808);      // [64][1024] bf16        131,072
  float*  Uloc  = (float*) (w + 38010880);      // [16384][64] f32      4,194,304
  float*  carry = (float*) (w + 42205184);      // [1024][64] f32         262,144
  float*  aSig  = (float*) (w + 42467328);      // [64] f32

  (void)hipFuncSetAttribute(reinterpret_cast<const void*>(&gemm128),
                            hipFuncAttributeMaxDynamicSharedMemorySize, 65536);

  prep_wb<<<dim3(288), dim3(256), 0, stream>>>(A_diag, B, C, D, Wt, Btu, aSig);
  fused_xu<<<dim3(512), dim3(256), 0, stream>>>(x, Btu, aSig, Z, Uloc, carry);
  scan_fix2<<<dim3(256), dim3(256), 0, stream>>>(aSig, Uloc, carry, Z);
  // y = [h|x] @ [C;D] : M=16384, N=1024, K=1088  (128x128 tiles -> 1024 blocks, 2/CU)
  gemm128<<<dim3(128 * 8), dim3(512), 65536, stream>>>(Z, KBIG, Wt, KBIG, y, DMODEL, KBIG);
}

// Round 17
// 83.664 us; speedup vs baseline: 2.1779x; 1.0081x over previous
//
#include <hip/hip_runtime.h>
#include <hip/hip_bf16.h>

using bf16x8 = __attribute__((ext_vector_type(8))) __bf16;
using f32x4  = __attribute__((ext_vector_type(4))) float;

#define MTOT   16384
#define DMODEL 1024
#define DSTATE 64
#define KBIG   1088

__device__ __forceinline__ ushort f2b(float f) {
  __hip_bfloat16 h = __float2bfloat16(f);
  return *reinterpret_cast<ushort*>(&h);
}

// async global->LDS, 16 bytes per lane. LDS dest = wave-uniform base + lane*16.
__device__ __forceinline__ void gld_lds16(const ushort* g, const char* l) {
  using gptr_t = const __attribute__((address_space(1))) uint32_t*;
  using lptr_t = __attribute__((address_space(3))) uint32_t*;
  __builtin_amdgcn_global_load_lds(
      reinterpret_cast<gptr_t>(reinterpret_cast<uintptr_t>(g)),
      reinterpret_cast<lptr_t>(static_cast<uint32_t>(reinterpret_cast<uintptr_t>(l))),
      16, 0, 0);
}

#define BARRIER() do { asm volatile("" ::: "memory"); __builtin_amdgcn_s_barrier(); asm volatile("" ::: "memory"); } while (0)
#define VMCNT8() asm volatile("s_waitcnt vmcnt(8)" ::: "memory")
#define VMCNT0() asm volatile("s_waitcnt vmcnt(0)" ::: "memory")

// ---------------- prep: coalesced tile-transpose for Wt, Btu; aSig (R12-proven) --------
__global__ __launch_bounds__(256) void prep_wb(const float* __restrict__ A_diag,
    const float* __restrict__ B, const float* __restrict__ C, const float* __restrict__ D,
    ushort* __restrict__ Wt, ushort* __restrict__ Btu, float* __restrict__ aSig) {
  __shared__ float tile[64][65];
  int bid = blockIdx.x;
  int tid = threadIdx.x;
  int r = tid >> 2;
  if (bid < 272) {
    int bk = bid % 17, bn = bid / 17;
    int k0 = bk * 64, n0 = bn * 64;
    const float* srow = (k0 + r < DSTATE)
        ? (C + (size_t)(k0 + r) * DMODEL + n0)
        : (D + (size_t)(k0 + r - DSTATE) * DMODEL + n0);
#pragma unroll
    for (int it = 0; it < 4; ++it) {
      int c4 = (tid & 3) + it * 4;
      float4 v = *reinterpret_cast<const float4*>(srow + c4 * 4);
      tile[r][c4 * 4 + 0] = v.x; tile[r][c4 * 4 + 1] = v.y;
      tile[r][c4 * 4 + 2] = v.z; tile[r][c4 * 4 + 3] = v.w;
    }
    __syncthreads();
#pragma unroll
    for (int it = 0; it < 2; ++it) {
      int gq = (tid & 3) + it * 4;  // 8-k group 0..7
      ushort o[8];
#pragma unroll
      for (int j = 0; j < 8; ++j) o[j] = f2b(tile[gq * 8 + j][r]);
      *reinterpret_cast<uint4*>(&Wt[(size_t)(n0 + r) * KBIG + k0 + gq * 8]) =
          *reinterpret_cast<uint4*>(o);
    }
  } else {
    int k0 = (bid - 272) * 64;
    const float* srow = B + (size_t)(k0 + r) * DSTATE;
#pragma unroll
    for (int it = 0; it < 4; ++it) {
      int c4 = (tid & 3) + it * 4;
      float4 v = *reinterpret_cast<const float4*>(srow + c4 * 4);
      tile[r][c4 * 4 + 0] = v.x; tile[r][c4 * 4 + 1] = v.y;
      tile[r][c4 * 4 + 2] = v.z; tile[r][c4 * 4 + 3] = v.w;
    }
    __syncthreads();
#pragma unroll
    for (int it = 0; it < 2; ++it) {
      int gq = (tid & 3) + it * 4;
      ushort o[8];
#pragma unroll
      for (int j = 0; j < 8; ++j) o[j] = f2b(tile[gq * 8 + j][r]);
      *reinterpret_cast<uint4*>(&Btu[(size_t)r * DMODEL + k0 + gq * 8]) =
          *reinterpret_cast<uint4*>(o);
    }
    if (bid == 272 && tid < DSTATE) aSig[tid] = 1.0f / (1.0f + expf(-A_diag[tid]));
  }
}

// ---------------- fused v2 (R16-proven, 2 blocks/CU): x -> Z, u = x@B, chunk scan -------
__global__ __launch_bounds__(256) void fused_xu(const float* __restrict__ x,
    const ushort* __restrict__ Btu, const float* __restrict__ aSig,
    ushort* __restrict__ Z, float* __restrict__ Uloc, float* __restrict__ carry) {
  __shared__ ushort As[32][136];
  __shared__ float  Ul[32][68];
  int tid = threadIdx.x;
  int w = tid >> 6, lane = tid & 63;
  int l16 = lane & 15, lh = lane >> 4;
  int row0 = blockIdx.x * 32;
  int cr0 = (w >> 1) * 16;   // A-frag row base
  int nb = (w & 1) * 2;      // B n-base (states nb*16..nb*16+31)

  f32x4 acc[2] = {};
  float4 xv[2][2];
#pragma unroll
  for (int p = 0; p < 2; ++p) {
    int fi = p * 256 + tid;
    int r = fi >> 4, kq = fi & 15;
    const float* src = x + (size_t)(row0 + r) * 1024 + kq * 8;
    xv[p][0] = *reinterpret_cast<const float4*>(src);
    xv[p][1] = *reinterpret_cast<const float4*>(src + 4);
  }
  for (int c = 0; c < 8; ++c) {
    int k0 = c * 128;
#pragma unroll
    for (int p = 0; p < 2; ++p) {
      int fi = p * 256 + tid;
      int r = fi >> 4, kq = fi & 15;
      ushort o[8] = {f2b(xv[p][0].x), f2b(xv[p][0].y), f2b(xv[p][0].z), f2b(xv[p][0].w),
                     f2b(xv[p][1].x), f2b(xv[p][1].y), f2b(xv[p][1].z), f2b(xv[p][1].w)};
      uint4 pk = *reinterpret_cast<uint4*>(o);
      *reinterpret_cast<uint4*>(&Z[(size_t)(row0 + r) * KBIG + DSTATE + k0 + kq * 8]) = pk;
      *reinterpret_cast<uint4*>(&As[r][kq * 8]) = pk;
    }
    __syncthreads();
    if (c < 7) {
      int k1 = k0 + 128;
#pragma unroll
      for (int p = 0; p < 2; ++p) {
        int fi = p * 256 + tid;
        int r = fi >> 4, kq = fi & 15;
        const float* src = x + (size_t)(row0 + r) * 1024 + k1 + kq * 8;
        xv[p][0] = *reinterpret_cast<const float4*>(src);
        xv[p][1] = *reinterpret_cast<const float4*>(src + 4);
      }
    }
#pragma unroll
    for (int ks = 0; ks < 4; ++ks) {
      bf16x8 af = *reinterpret_cast<const bf16x8*>(&As[cr0 + l16][ks * 32 + lh * 8]);
#pragma unroll
      for (int n2 = 0; n2 < 2; ++n2) {
        bf16x8 bf = *reinterpret_cast<const bf16x8*>(
            &Btu[(size_t)((nb + n2) * 16 + l16) * 1024 + k0 + ks * 32 + lh * 8]);
        acc[n2] = __builtin_amdgcn_mfma_f32_16x16x32_bf16(af, bf, acc[n2], 0, 0, 0);
      }
    }
    __syncthreads();
  }
#pragma unroll
  for (int n2 = 0; n2 < 2; ++n2)
#pragma unroll
    for (int j = 0; j < 4; ++j)
      Ul[cr0 + lh * 4 + j][(nb + n2) * 16 + l16] = acc[n2][j];
  __syncthreads();
  if (w < 2) {
    int g = blockIdx.x * 2 + w;
    float as = aSig[lane];
    float h = 0.0f;
#pragma unroll
    for (int i = 0; i < 16; ++i) {
      h = fmaf(as, h, Ul[w * 16 + i][lane]);
      Uloc[(size_t)(g * 16 + i) * 64 + lane] = h;
    }
    carry[(size_t)g * 64 + lane] = h;
  }
}

// ---------------- scan fix (merged): redundant batched prefix + apply + write Z ------
__global__ __launch_bounds__(256) void scan_fix2(const float* __restrict__ aSig,
    const float* __restrict__ Uloc, const float* __restrict__ carry,
    ushort* __restrict__ Z) {
  int w = threadIdx.x >> 6, s = threadIdx.x & 63;
  int g = blockIdx.x * 4 + w;          // 0..1023
  int b = g >> 8, c = g & 255;
  float as = aSig[s];
  float aL = as;
#pragma unroll
  for (int q = 0; q < 4; ++q) aL *= aL;  // as^16
  const float* cb = carry + ((size_t)b << 8) * 64 + s;
  float H = 0.0f;
  for (int c0 = 0; c0 < 256; c0 += 16) {
    if (c0 >= c) break;                  // wave-uniform
    float v[16];
#pragma unroll
    for (int i = 0; i < 16; ++i) v[i] = cb[(size_t)(c0 + i) * 64];
#pragma unroll
    for (int i = 0; i < 16; ++i)
      if (c0 + i < c) H = fmaf(aL, H, v[i]);   // wave-uniform predicate
  }
  float p = as;
  size_t ubase = (size_t)g * 16 * 64 + s;
  size_t zbase = (size_t)(g * 16) * KBIG + s;
#pragma unroll
  for (int i = 0; i < 16; ++i) {
    float h = fmaf(p, H, Uloc[ubase + (size_t)i * 64]);
    p *= as;
    Z[zbase + (size_t)i * KBIG] = f2b(h);
  }
}

// ---------------- 128x128 GEMM v2: 4 waves (2x2), 64x64 wave-tile ----------------
// LDS-redundancy fix: A read 2x, B read 2x (was A 4x, B 2x) -> 96KB LDS traffic
// per k-tile (was 128KB). Same proven stage/swizzle/read pattern, 64KB dbuf,
// 2 blocks/CU. 256 thr; launch_bounds(256,2) -> 256-reg budget (frag 64 + acc 64
// + addr fits, no spill). Stage: 8 gld calls/tile (4A+4B, each wave 1KB rows
// wid*8+h*32). vmcnt(8) counted: drains t+1's 8, leaves t+2's 8 in flight.
__global__ __launch_bounds__(256, 2) void gemm128(const ushort* __restrict__ A, int lda,
                                                  const ushort* __restrict__ Bt, int ldb,
                                                  float* __restrict__ Cc, int ldc, int K) {
  extern __shared__ __align__(128) char smem[];  // buf{0,1} x (A 16K + B 16K) = 64 KB
  const int tid = threadIdx.x;
  const int wid = tid >> 6, lane = tid & 63;
  const int wm = wid >> 1, wn = wid & 1;          // 2 x 2 wave grid
  const int l16 = lane & 15, lh = lane >> 4;

  int bid = blockIdx.x;
  int swz = (bid & 7) * ((int)gridDim.x >> 3) + (bid >> 3);  // 1024 % 8 == 0
  const int bmRow = (swz >> 3) * 128;
  const int bnCol = (swz & 7) * 128;
  const int NT = K / 64;                // 17

  const int cswz = ((lh ^ (l16 & 7)) << 4);
  const int sRow = lane >> 3;
  const int sCol = (((lane & 7) ^ (lane >> 3)) << 3);

  // wave wid stages rows {wid*8+sRow} + h*32, h=0..3 (4 calls per operand)
  const ushort* aBase = A + (size_t)(bmRow + wid * 8 + sRow) * lda + sCol;
  const ushort* bBase = Bt + (size_t)(bnCol + wid * 8 + sRow) * ldb + sCol;

  f32x4 acc[4][4] = {};
  bf16x8 aR[8], bR[8];

  auto stageA = [&](int buf, int t) {
    const ushort* g = aBase + (size_t)t * 64;
    char* d = smem + buf * 32768 + (wid * 8) * 128;
#pragma unroll
    for (int h = 0; h < 4; ++h)
      gld_lds16(g + (size_t)(h * 32) * lda, d + h * 32 * 128);
  };
  auto stageB = [&](int buf, int t) {
    const ushort* g = bBase + (size_t)t * 64;
    char* d = smem + buf * 32768 + 16384 + (wid * 8) * 128;
#pragma unroll
    for (int h = 0; h < 4; ++h)
      gld_lds16(g + (size_t)(h * 32) * ldb, d + h * 32 * 128);
  };
  auto readA = [&](int buf) {
#pragma unroll
    for (int m = 0; m < 4; ++m)
#pragma unroll
      for (int ks = 0; ks < 2; ++ks)
        aR[m * 2 + ks] = *reinterpret_cast<const bf16x8*>(
            smem + buf * 32768 + (wm * 64 + m * 16 + l16) * 128 + (cswz ^ (ks * 64)));
  };
  auto readB = [&](int buf) {
#pragma unroll
    for (int n = 0; n < 4; ++n)
#pragma unroll
      for (int ks = 0; ks < 2; ++ks)
        bR[n * 2 + ks] = *reinterpret_cast<const bf16x8*>(
            smem + buf * 32768 + 16384 + (wn * 64 + n * 16 + l16) * 128 + (cswz ^ (ks * 64)));
  };

  // prologue: stage tiles 0,1 (16 calls); drain tile0 (tile1's 8 in flight)
  stageA(0, 0); stageB(0, 0);
  stageA(1, 1); stageB(1, 1);
  VMCNT8();
  BARRIER();

  for (int t = 0; t < NT; ++t) {
    const int buf = t & 1;
    const bool st2 = (t + 2 < NT);
    readA(buf); readB(buf);
    BARRIER();                     // all reads of buf issued block-wide
    if (st2) { stageA(buf, t + 2); stageB(buf, t + 2); }
    __builtin_amdgcn_s_setprio(1);
#pragma unroll
    for (int ks = 0; ks < 2; ++ks)
#pragma unroll
      for (int m = 0; m < 4; ++m)
#pragma unroll
        for (int n = 0; n < 4; ++n)
          acc[m][n] = __builtin_amdgcn_mfma_f32_16x16x32_bf16(
              aR[m * 2 + ks], bR[n * 2 + ks], acc[m][n], 0, 0, 0);
    __builtin_amdgcn_s_setprio(0);
    if (st2) { VMCNT8(); } else { VMCNT0(); }   // drain t+1's stages; t+2's in flight
    BARRIER();                     // publish buf^1 (tile t+1)
  }

  // epilogue: C/D 16x16 layout: col = l16, row = lh*4 + j
#pragma unroll
  for (int m = 0; m < 4; ++m)
#pragma unroll
    for (int n = 0; n < 4; ++n)
#pragma unroll
      for (int j = 0; j < 4; ++j) {
        int r = bmRow + wm * 64 + m * 16 + lh * 4 + j;
        int c = bnCol + wn * 64 + n * 16 + l16;
        Cc[(size_t)r * ldc + c] = acc[m][n][j];
      }
}

extern "C" void kernel_launch(void* const* d_in, const int* in_sizes, int n_in,
                              void* d_out, int out_size, void* d_ws, size_t ws_size,
                              hipStream_t stream) {
  const float* x      = (const float*)d_in[0];
  const float* A_diag = (const float*)d_in[1];
  const float* B      = (const float*)d_in[2];
  const float* C      = (const float*)d_in[3];
  const float* D      = (const float*)d_in[4];
  float* y = (float*)d_out;

  char* w = (char*)d_ws;
  ushort* Z     = (ushort*)(w);                 // [16384][1088] bf16  35,651,584
  ushort* Wt    = (ushort*)(w + 35651584);      // [1024][1088] bf16    2,228,224
  ushort* Btu   = (ushort*)(w + 37879808);      // [64][1024] bf16        131,072
  float*  Uloc  = (float*) (w + 38010880);      // [16384][64] f32      4,194,304
  float*  carry = (float*) (w + 42205184);      // [1024][64] f32         262,144
  float*  aSig  = (float*) (w + 42467328);      // [64] f32

  (void)hipFuncSetAttribute(reinterpret_cast<const void*>(&gemm128),
                            hipFuncAttributeMaxDynamicSharedMemorySize, 65536);

  prep_wb<<<dim3(288), dim3(256), 0, stream>>>(A_diag, B, C, D, Wt, Btu, aSig);
  fused_xu<<<dim3(512), dim3(256), 0, stream>>>(x, Btu, aSig, Z, Uloc, carry);
  scan_fix2<<<dim3(256), dim3(256), 0, stream>>>(aSig, Uloc, carry, Z);
  // y = [h|x] @ [C;D] : M=16384, N=1024, K=1088  (128x128 tiles -> 1024 blocks, 2/CU)
  gemm128<<<dim3(128 * 8), dim3(256), 65536, stream>>>(Z, KBIG, Wt, KBIG, y, DMODEL, KBIG);
}

// Round 18
// 82.682 us; speedup vs baseline: 2.2038x; 1.0119x over previous
//
#include <hip/hip_runtime.h>
#include <hip/hip_bf16.h>

using bf16x8 = __attribute__((ext_vector_type(8))) __bf16;
using f32x4  = __attribute__((ext_vector_type(4))) float;

#define MTOT   16384
#define DMODEL 1024
#define DSTATE 64
#define KBIG   1088

__device__ __forceinline__ ushort f2b(float f) {
  __hip_bfloat16 h = __float2bfloat16(f);
  return *reinterpret_cast<ushort*>(&h);
}

// async global->LDS, 16 bytes per lane. LDS dest = wave-uniform base + lane*16.
__device__ __forceinline__ void gld_lds16(const ushort* g, const char* l) {
  using gptr_t = const __attribute__((address_space(1))) uint32_t*;
  using lptr_t = __attribute__((address_space(3))) uint32_t*;
  __builtin_amdgcn_global_load_lds(
      reinterpret_cast<gptr_t>(reinterpret_cast<uintptr_t>(g)),
      reinterpret_cast<lptr_t>(static_cast<uint32_t>(reinterpret_cast<uintptr_t>(l))),
      16, 0, 0);
}

#define BARRIER() do { asm volatile("" ::: "memory"); __builtin_amdgcn_s_barrier(); asm volatile("" ::: "memory"); } while (0)
#define VMCNT8() asm volatile("s_waitcnt vmcnt(8)" ::: "memory")
#define VMCNT0() asm volatile("s_waitcnt vmcnt(0)" ::: "memory")

// ---------------- prep: coalesced tile-transpose for Wt, Btu; aSig (R12-proven) --------
__global__ __launch_bounds__(256) void prep_wb(const float* __restrict__ A_diag,
    const float* __restrict__ B, const float* __restrict__ C, const float* __restrict__ D,
    ushort* __restrict__ Wt, ushort* __restrict__ Btu, float* __restrict__ aSig) {
  __shared__ float tile[64][65];
  int bid = blockIdx.x;
  int tid = threadIdx.x;
  int r = tid >> 2;
  if (bid < 272) {
    int bk = bid % 17, bn = bid / 17;
    int k0 = bk * 64, n0 = bn * 64;
    const float* srow = (k0 + r < DSTATE)
        ? (C + (size_t)(k0 + r) * DMODEL + n0)
        : (D + (size_t)(k0 + r - DSTATE) * DMODEL + n0);
#pragma unroll
    for (int it = 0; it < 4; ++it) {
      int c4 = (tid & 3) + it * 4;
      float4 v = *reinterpret_cast<const float4*>(srow + c4 * 4);
      tile[r][c4 * 4 + 0] = v.x; tile[r][c4 * 4 + 1] = v.y;
      tile[r][c4 * 4 + 2] = v.z; tile[r][c4 * 4 + 3] = v.w;
    }
    __syncthreads();
#pragma unroll
    for (int it = 0; it < 2; ++it) {
      int gq = (tid & 3) + it * 4;  // 8-k group 0..7
      ushort o[8];
#pragma unroll
      for (int j = 0; j < 8; ++j) o[j] = f2b(tile[gq * 8 + j][r]);
      *reinterpret_cast<uint4*>(&Wt[(size_t)(n0 + r) * KBIG + k0 + gq * 8]) =
          *reinterpret_cast<uint4*>(o);
    }
  } else {
    int k0 = (bid - 272) * 64;
    const float* srow = B + (size_t)(k0 + r) * DSTATE;
#pragma unroll
    for (int it = 0; it < 4; ++it) {
      int c4 = (tid & 3) + it * 4;
      float4 v = *reinterpret_cast<const float4*>(srow + c4 * 4);
      tile[r][c4 * 4 + 0] = v.x; tile[r][c4 * 4 + 1] = v.y;
      tile[r][c4 * 4 + 2] = v.z; tile[r][c4 * 4 + 3] = v.w;
    }
    __syncthreads();
#pragma unroll
    for (int it = 0; it < 2; ++it) {
      int gq = (tid & 3) + it * 4;
      ushort o[8];
#pragma unroll
      for (int j = 0; j < 8; ++j) o[j] = f2b(tile[gq * 8 + j][r]);
      *reinterpret_cast<uint4*>(&Btu[(size_t)r * DMODEL + k0 + gq * 8]) =
          *reinterpret_cast<uint4*>(o);
    }
    if (bid == 272 && tid < DSTATE) aSig[tid] = 1.0f / (1.0f + expf(-A_diag[tid]));
  }
}

// ---------------- fused v3 (deep TLP): x -> Z(bf16), u = x@B, chunk scan ----------
// 1024 blocks x 16 rows, 4 waves, LDS 8.5KB -> ~8 blocks/CU (wave-slot-capped).
// Each thread stages ONE ushort8 per 128-k chunk (tid>>4 = row, tid&15 = k-group).
// Wave w computes B-quadrant n=w (1 acc). Chunk id g = blockIdx.x (global order
// preserved for scan_fix2: 1024 chunks x 16 rows).
__global__ __launch_bounds__(256) void fused_xu(const float* __restrict__ x,
    const ushort* __restrict__ Btu, const float* __restrict__ aSig,
    ushort* __restrict__ Z, float* __restrict__ Uloc, float* __restrict__ carry) {
  __shared__ ushort As[16][136];
  __shared__ float  Ul[16][68];
  int tid = threadIdx.x;
  int w = tid >> 6, lane = tid & 63;
  int l16 = lane & 15, lh = lane >> 4;
  int row0 = blockIdx.x * 16;
  int r = tid >> 4, kq = tid & 15;

  f32x4 acc = {};
  const float* srcBase = x + (size_t)(row0 + r) * 1024 + kq * 8;
  float4 xv0 = *reinterpret_cast<const float4*>(srcBase);
  float4 xv1 = *reinterpret_cast<const float4*>(srcBase + 4);
  for (int c = 0; c < 8; ++c) {
    int k0 = c * 128;
    ushort o[8] = {f2b(xv0.x), f2b(xv0.y), f2b(xv0.z), f2b(xv0.w),
                   f2b(xv1.x), f2b(xv1.y), f2b(xv1.z), f2b(xv1.w)};
    uint4 pk = *reinterpret_cast<uint4*>(o);
    *reinterpret_cast<uint4*>(&Z[(size_t)(row0 + r) * KBIG + DSTATE + k0 + kq * 8]) = pk;
    *reinterpret_cast<uint4*>(&As[r][kq * 8]) = pk;
    __syncthreads();
    if (c < 7) {
      const float* src = srcBase + k0 + 128;
      xv0 = *reinterpret_cast<const float4*>(src);
      xv1 = *reinterpret_cast<const float4*>(src + 4);
    }
#pragma unroll
    for (int ks = 0; ks < 4; ++ks) {
      bf16x8 af = *reinterpret_cast<const bf16x8*>(&As[l16][ks * 32 + lh * 8]);
      bf16x8 bf = *reinterpret_cast<const bf16x8*>(
          &Btu[(size_t)(w * 16 + l16) * 1024 + k0 + ks * 32 + lh * 8]);
      acc = __builtin_amdgcn_mfma_f32_16x16x32_bf16(af, bf, acc, 0, 0, 0);
    }
    __syncthreads();
  }
#pragma unroll
  for (int j = 0; j < 4; ++j)
    Ul[lh * 4 + j][w * 16 + l16] = acc[j];
  __syncthreads();
  if (w == 0) {
    int g = blockIdx.x;
    float as = aSig[lane];
    float h = 0.0f;
#pragma unroll
    for (int i = 0; i < 16; ++i) {
      h = fmaf(as, h, Ul[i][lane]);
      Uloc[(size_t)(g * 16 + i) * 64 + lane] = h;
    }
    carry[(size_t)g * 64 + lane] = h;
  }
}

// ---------------- scan fix v2 (2x blocks): batched prefix + apply + write Z ------
// 512 blocks x 128 thr (2 waves): g = bid*2 + w. Same math as R13-proven version.
__global__ __launch_bounds__(128) void scan_fix2(const float* __restrict__ aSig,
    const float* __restrict__ Uloc, const float* __restrict__ carry,
    ushort* __restrict__ Z) {
  int w = threadIdx.x >> 6, s = threadIdx.x & 63;
  int g = blockIdx.x * 2 + w;          // 0..1023
  int b = g >> 8, c = g & 255;
  float as = aSig[s];
  float aL = as;
#pragma unroll
  for (int q = 0; q < 4; ++q) aL *= aL;  // as^16
  const float* cb = carry + ((size_t)b << 8) * 64 + s;
  float H = 0.0f;
  for (int c0 = 0; c0 < 256; c0 += 16) {
    if (c0 >= c) break;                  // wave-uniform
    float v[16];
#pragma unroll
    for (int i = 0; i < 16; ++i) v[i] = cb[(size_t)(c0 + i) * 64];
#pragma unroll
    for (int i = 0; i < 16; ++i)
      if (c0 + i < c) H = fmaf(aL, H, v[i]);   // wave-uniform predicate
  }
  float p = as;
  size_t ubase = (size_t)g * 16 * 64 + s;
  size_t zbase = (size_t)(g * 16) * KBIG + s;
#pragma unroll
  for (int i = 0; i < 16; ++i) {
    float h = fmaf(p, H, Uloc[ubase + (size_t)i * 64]);
    p *= as;
    Z[zbase + (size_t)i * KBIG] = f2b(h);
  }
}

// ---------------- 128x128 GEMM v2 (R17, LOCKED): 4 waves (2x2), 64x64 wave-tile --------
__global__ __launch_bounds__(256, 2) void gemm128(const ushort* __restrict__ A, int lda,
                                                  const ushort* __restrict__ Bt, int ldb,
                                                  float* __restrict__ Cc, int ldc, int K) {
  extern __shared__ __align__(128) char smem[];  // buf{0,1} x (A 16K + B 16K) = 64 KB
  const int tid = threadIdx.x;
  const int wid = tid >> 6, lane = tid & 63;
  const int wm = wid >> 1, wn = wid & 1;          // 2 x 2 wave grid
  const int l16 = lane & 15, lh = lane >> 4;

  int bid = blockIdx.x;
  int swz = (bid & 7) * ((int)gridDim.x >> 3) + (bid >> 3);  // 1024 % 8 == 0
  const int bmRow = (swz >> 3) * 128;
  const int bnCol = (swz & 7) * 128;
  const int NT = K / 64;                // 17

  const int cswz = ((lh ^ (l16 & 7)) << 4);
  const int sRow = lane >> 3;
  const int sCol = (((lane & 7) ^ (lane >> 3)) << 3);

  const ushort* aBase = A + (size_t)(bmRow + wid * 8 + sRow) * lda + sCol;
  const ushort* bBase = Bt + (size_t)(bnCol + wid * 8 + sRow) * ldb + sCol;

  f32x4 acc[4][4] = {};
  bf16x8 aR[8], bR[8];

  auto stageA = [&](int buf, int t) {
    const ushort* g = aBase + (size_t)t * 64;
    char* d = smem + buf * 32768 + (wid * 8) * 128;
#pragma unroll
    for (int h = 0; h < 4; ++h)
      gld_lds16(g + (size_t)(h * 32) * lda, d + h * 32 * 128);
  };
  auto stageB = [&](int buf, int t) {
    const ushort* g = bBase + (size_t)t * 64;
    char* d = smem + buf * 32768 + 16384 + (wid * 8) * 128;
#pragma unroll
    for (int h = 0; h < 4; ++h)
      gld_lds16(g + (size_t)(h * 32) * ldb, d + h * 32 * 128);
  };
  auto readA = [&](int buf) {
#pragma unroll
    for (int m = 0; m < 4; ++m)
#pragma unroll
      for (int ks = 0; ks < 2; ++ks)
        aR[m * 2 + ks] = *reinterpret_cast<const bf16x8*>(
            smem + buf * 32768 + (wm * 64 + m * 16 + l16) * 128 + (cswz ^ (ks * 64)));
  };
  auto readB = [&](int buf) {
#pragma unroll
    for (int n = 0; n < 4; ++n)
#pragma unroll
      for (int ks = 0; ks < 2; ++ks)
        bR[n * 2 + ks] = *reinterpret_cast<const bf16x8*>(
            smem + buf * 32768 + 16384 + (wn * 64 + n * 16 + l16) * 128 + (cswz ^ (ks * 64)));
  };

  stageA(0, 0); stageB(0, 0);
  stageA(1, 1); stageB(1, 1);
  VMCNT8();
  BARRIER();

  for (int t = 0; t < NT; ++t) {
    const int buf = t & 1;
    const bool st2 = (t + 2 < NT);
    readA(buf); readB(buf);
    BARRIER();                     // all reads of buf issued block-wide
    if (st2) { stageA(buf, t + 2); stageB(buf, t + 2); }
    __builtin_amdgcn_s_setprio(1);
#pragma unroll
    for (int ks = 0; ks < 2; ++ks)
#pragma unroll
      for (int m = 0; m < 4; ++m)
#pragma unroll
        for (int n = 0; n < 4; ++n)
          acc[m][n] = __builtin_amdgcn_mfma_f32_16x16x32_bf16(
              aR[m * 2 + ks], bR[n * 2 + ks], acc[m][n], 0, 0, 0);
    __builtin_amdgcn_s_setprio(0);
    if (st2) { VMCNT8(); } else { VMCNT0(); }   // drain t+1's stages; t+2's in flight
    BARRIER();                     // publish buf^1 (tile t+1)
  }

  // epilogue: C/D 16x16 layout: col = l16, row = lh*4 + j
#pragma unroll
  for (int m = 0; m < 4; ++m)
#pragma unroll
    for (int n = 0; n < 4; ++n)
#pragma unroll
      for (int j = 0; j < 4; ++j) {
        int r = bmRow + wm * 64 + m * 16 + lh * 4 + j;
        int c = bnCol + wn * 64 + n * 16 + l16;
        Cc[(size_t)r * ldc + c] = acc[m][n][j];
      }
}

extern "C" void kernel_launch(void* const* d_in, const int* in_sizes, int n_in,
                              void* d_out, int out_size, void* d_ws, size_t ws_size,
                              hipStream_t stream) {
  const float* x      = (const float*)d_in[0];
  const float* A_diag = (const float*)d_in[1];
  const float* B      = (const float*)d_in[2];
  const float* C      = (const float*)d_in[3];
  const float* D      = (const float*)d_in[4];
  float* y = (float*)d_out;

  char* w = (char*)d_ws;
  ushort* Z     = (ushort*)(w);                 // [16384][1088] bf16  35,651,584
  ushort* Wt    = (ushort*)(w + 35651584);      // [1024][1088] bf16    2,228,224
  ushort* Btu   = (ushort*)(w + 37879808);      // [64][1024] bf16        131,072
  float*  Uloc  = (float*) (w + 38010880);      // [16384][64] f32      4,194,304
  float*  carry = (float*) (w + 42205184);      // [1024][64] f32         262,144
  float*  aSig  = (float*) (w + 42467328);      // [64] f32

  (void)hipFuncSetAttribute(reinterpret_cast<const void*>(&gemm128),
                            hipFuncAttributeMaxDynamicSharedMemorySize, 65536);

  prep_wb<<<dim3(288), dim3(256), 0, stream>>>(A_diag, B, C, D, Wt, Btu, aSig);
  fused_xu<<<dim3(1024), dim3(256), 0, stream>>>(x, Btu, aSig, Z, Uloc, carry);
  scan_fix2<<<dim3(512), dim3(128), 0, stream>>>(aSig, Uloc, carry, Z);
  // y = [h|x] @ [C;D] : M=16384, N=1024, K=1088  (128x128 tiles -> 1024 blocks, 2/CU)
  gemm128<<<dim3(128 * 8), dim3(256), 65536, stream>>>(Z, KBIG, Wt, KBIG, y, DMODEL, KBIG);
}